// Round 7
// baseline (259.472 us; speedup 1.0000x reference)
//
#include <hip/hip_runtime.h>
#include <hip/hip_bf16.h>
#include <stdint.h>

// B=16, TH=TS=HS=WS=1024
// res[b,i,o] = sum_j softmax_j(hp[b,i,:].sp[b,j,:]) * hp[b,j,o]
// hp = h*Wh^T + bh ; sp = s*Ws^T + bs
// fp16 operands, f32 MFMA accum. 256^2 8-phase GEMM with DEEP prefetch:
// tile t+2 staged at q2 (B) / q3 (A); single vmcnt(8) gate per K-step waits
// only on tile t+1 loads issued 4-5 phases earlier (never exposes HBM latency).

typedef _Float16 half_t;
typedef __attribute__((ext_vector_type(8))) _Float16 half8;   // 4 VGPR
typedef __attribute__((ext_vector_type(4))) _Float16 half4;
typedef __attribute__((ext_vector_type(4))) float floatx4;

__device__ __forceinline__ void gl2lds16(const void* g, void* l) {
    __builtin_amdgcn_global_load_lds(
        (const __attribute__((address_space(1))) uint32_t*)(uintptr_t)g,
        (__attribute__((address_space(3))) uint32_t*)(uintptr_t)l,
        16, 0, 0);
}

// barrier -> wait LDS data -> fence (rule #18); compiler also tracks plain reads
#define PH_MID() do { \
    __builtin_amdgcn_s_barrier(); \
    asm volatile("s_waitcnt lgkmcnt(0)" ::: "memory"); \
    __builtin_amdgcn_sched_barrier(0); } while (0)

#define PH_END() __builtin_amdgcn_s_barrier()

#define QUAD(mq, nq) do { \
    __builtin_amdgcn_s_setprio(1); \
    _Pragma("unroll") for (int mi = 0; mi < 4; ++mi) \
    _Pragma("unroll") for (int ni = 0; ni < 2; ++ni) \
    _Pragma("unroll") for (int ks = 0; ks < 2; ++ks) \
        acc[(mq)*4+mi][(nq)*2+ni] = __builtin_amdgcn_mfma_f32_16x16x32_f16( \
            aF[mi][ks], bF[nq][ni][ks], acc[(mq)*4+mi][(nq)*2+ni], 0, 0, 0); \
    __builtin_amdgcn_s_setprio(0); } while (0)

#define NT16 16   // K = 1024, BK = 64

// C[r][c] = sum_k A[r][k]*B[c][k] (+bias[c]); operands K-major (B^T GEMM), fp16.
// 256x256 tile, 8 waves (2Mx4N), per-wave 128x64, double-buffered 128KB LDS.
// Swizzle: rows are 128B (=32 banks); XOR byte bits 4-6 with row&7 spreads
// 8 rows over all 8 16B slots (both-sides: pre-swizzled global src + read).
template<int WF32, int WH16, int WH16T>
__global__ __launch_bounds__(512, 2) void gemm256(
    const half_t* __restrict__ A, const half_t* __restrict__ B,
    const float* __restrict__ bias,
    float* __restrict__ Cf, half_t* __restrict__ Ch, half_t* __restrict__ ChT,
    int lda, int ldb, int N,
    long aBatch, long bBatch, long cfBatch, int ldcf)
{
    extern __shared__ char smem[];   // [2][ A:32KB | B:32KB ] = 128KB

    const int tid  = threadIdx.x;
    const int wave = tid >> 6;
    const int lane = tid & 63;
    const int wr = wave >> 2;        // 0..1 -> rows wr*128..+127
    const int wc = wave & 3;         // 0..3 -> cols wc*64..+63
    const int lr = lane & 15, lg = lane >> 4;

    const long batch = blockIdx.z;
    const half_t* Ab = A + batch * aBatch;
    const half_t* Bb = B + batch * bBatch;
    const int row0 = blockIdx.x * 256;
    const int col0 = blockIdx.y * 256;

    floatx4 acc[8][4];
#pragma unroll
    for (int m = 0; m < 8; ++m)
#pragma unroll
        for (int n = 0; n < 4; ++n)
            acc[m][n] = (floatx4){0.f, 0.f, 0.f, 0.f};

    // hand-hoisted stage source offsets (bytes, excl. kk*2): per (half,i)
    // off bits 7-9 = row&7; inverse-swizzle XOR into bits 4-6 (involution).
    long aOff[2][2], bOff[2][2];
#pragma unroll
    for (int hh = 0; hh < 2; ++hh)
#pragma unroll
        for (int i = 0; i < 2; ++i) {
            const int off = hh * 16384 + i * 8192 + tid * 16;
            const int e = off ^ (((off >> 7) & 7) << 4);
            const int r = e >> 7, cb = e & 127;     // 128B per tile row
            aOff[hh][i] = (long)(row0 + r) * (long)(lda * 2) + cb;
            bOff[hh][i] = (long)(col0 + r) * (long)(ldb * 2) + cb;
        }

    auto stageHalf = [&](int buf, int isA, int hh, int kk) {
#pragma unroll
        for (int i = 0; i < 2; ++i) {
            const char* g = (isA ? (const char*)Ab + aOff[hh][i]
                                 : (const char*)Bb + bOff[hh][i]) + (long)kk * 2;
            gl2lds16(g, smem + buf * 65536 + (isA ? 0 : 32768)
                          + hh * 16384 + i * 8192 + wave * 1024);
        }
    };
    auto ldA = [&](int buf, int mt, int ks) -> half8 {
        const int row = wr * 128 + mt * 16 + lr;                 // row&7 == lr&7
        const int kp = (ks * 64 + lg * 16) ^ ((row & 7) << 4);
        return *(const half8*)(smem + buf * 65536 + row * 128 + kp);
    };
    auto ldB = [&](int buf, int nt, int ks) -> half8 {
        const int row = wc * 64 + nt * 16 + lr;
        const int kp = (ks * 64 + lg * 16) ^ ((row & 7) << 4);
        return *(const half8*)(smem + buf * 65536 + 32768 + row * 128 + kp);
    };

    // ---- prologue: stage tiles 0 and 1 fully; retire tile 0 (leave tile 1's
    // 8 insts in flight), barrier.
    stageHalf(0, 0, 0, 0);   stageHalf(0, 0, 1, 0);     // tile0 B0,B1
    stageHalf(0, 1, 0, 0);   stageHalf(0, 1, 1, 0);     // tile0 A0,A1
    stageHalf(1, 0, 0, 64);  stageHalf(1, 0, 1, 64);    // tile1 B0,B1
    stageHalf(1, 1, 0, 64);  stageHalf(1, 1, 1, 64);    // tile1 A0,A1
    asm volatile("s_waitcnt vmcnt(8)" ::: "memory");
    __builtin_amdgcn_s_barrier();

    half8 aF[4][2];          // current A m-quadrant (4 m-tiles x 2 ksub)
    half8 bF[2][2][2];       // both B n-quadrants (persist q0->q3)

#pragma unroll 2
    for (int t = 0; t < NT16; ++t) {
        const int cur = t & 1;
        const int kk2 = (t + 2) * 64;

        // ---- q0: read aF-low + bF[0]; no staging
#pragma unroll
        for (int mi = 0; mi < 4; ++mi)
#pragma unroll
            for (int ks = 0; ks < 2; ++ks) aF[mi][ks] = ldA(cur, mi, ks);
#pragma unroll
        for (int ni = 0; ni < 2; ++ni)
#pragma unroll
            for (int ks = 0; ks < 2; ++ks) bF[0][ni][ks] = ldB(cur, ni, ks);
        PH_MID();
        QUAD(0, 0);
        PH_END();

        // ---- q1: read bF[1]; no staging (B region of buf[cur] still hot)
#pragma unroll
        for (int ni = 0; ni < 2; ++ni)
#pragma unroll
            for (int ks = 0; ks < 2; ++ks) bF[1][ni][ks] = ldB(cur, 2 + ni, ks);
        PH_MID();
        QUAD(0, 1);
        PH_END();

        // ---- q2: read aF-high; stage B(t+2) -> buf[cur] B region
        //      (safe: all waves' B reads of buf[cur] drained before q1 PH_END)
#pragma unroll
        for (int mi = 0; mi < 4; ++mi)
#pragma unroll
            for (int ks = 0; ks < 2; ++ks) aF[mi][ks] = ldA(cur, 4 + mi, ks);
        if (t + 2 < NT16) {
            stageHalf(cur, 0, 0, kk2);
            stageHalf(cur, 0, 1, kk2);
        }
        PH_MID();
        QUAD(1, 1);
        PH_END();

        // ---- q3: no reads; stage A(t+2) -> buf[cur] A region; gate vmcnt(8):
        //      retires tile t+1 (issued q2/q3 of step t-1, 4-5 phases old),
        //      keeps tile t+2's 8 insts in flight.
        if (t + 2 < NT16) {
            stageHalf(cur, 1, 0, kk2);
            stageHalf(cur, 1, 1, kk2);
            asm volatile("s_waitcnt vmcnt(8)" ::: "memory");
        } else {
            asm volatile("s_waitcnt vmcnt(0)" ::: "memory");   // tail (loads old, no stall)
        }
        PH_MID();
        QUAD(1, 0);
        PH_END();
    }

    // ---- epilogue: D frag layout col=lane&15, row=(lane>>4)*4+j
#pragma unroll
    for (int m = 0; m < 8; ++m) {
        const int gr0 = row0 + wr * 128 + m * 16 + lg * 4;
#pragma unroll
        for (int n = 0; n < 4; ++n) {
            const int gc = col0 + wc * 64 + n * 16 + lr;
            floatx4 v = acc[m][n];
            if (bias) {
                const float b = bias[gc];
                v[0] += b; v[1] += b; v[2] += b; v[3] += b;
            }
            if (WF32) {
                float* p = Cf + batch * cfBatch + (long)gr0 * ldcf + gc;
#pragma unroll
                for (int j = 0; j < 4; ++j) p[(long)j * ldcf] = v[j];
            }
            if (WH16) {
#pragma unroll
                for (int j = 0; j < 4; ++j)
                    Ch[(long)(gr0 + j) * N + gc] = (half_t)v[j];
            }
            if (WH16T) {
                const int b2 = gr0 >> 10;
                const int t0 = gr0 & 1023;
                half4 pk = { (half_t)v[0], (half_t)v[1], (half_t)v[2], (half_t)v[3] };
                *(half4*)&ChT[(long)b2 * 1048576 + (long)gc * 1024 + t0] = pk;
            }
        }
    }
}

// In-place: reads f32 row (1024), writes fp16 probabilities over its own first half.
__global__ void softmax_inplace(float* __restrict__ S) {
    const long r = blockIdx.x;
    float* row = S + r * 1024;
    const int tid = threadIdx.x;
    const int wave = tid >> 6, lane = tid & 63;

    float4 v = ((const float4*)row)[tid];
    float mx = fmaxf(fmaxf(v.x, v.y), fmaxf(v.z, v.w));
#pragma unroll
    for (int off = 32; off > 0; off >>= 1)
        mx = fmaxf(mx, __shfl_xor(mx, off));
    __shared__ float rmx[4], rsm[4];
    if (lane == 0) rmx[wave] = mx;
    __syncthreads();
    mx = fmaxf(fmaxf(rmx[0], rmx[1]), fmaxf(rmx[2], rmx[3]));

    float e0 = __expf(v.x - mx), e1 = __expf(v.y - mx);
    float e2 = __expf(v.z - mx), e3 = __expf(v.w - mx);
    float s = e0 + e1 + e2 + e3;
#pragma unroll
    for (int off = 32; off > 0; off >>= 1)
        s += __shfl_xor(s, off);
    if (lane == 0) rsm[wave] = s;
    __syncthreads();
    s = rsm[0] + rsm[1] + rsm[2] + rsm[3];

    const float inv = 1.0f / s;
    half4 o = { (half_t)(e0 * inv), (half_t)(e1 * inv), (half_t)(e2 * inv), (half_t)(e3 * inv) };
    ((half4*)((half_t*)S + r * 2048))[tid] = o;
}

__global__ void cvt_f16(const float4* __restrict__ src, half4* __restrict__ dst, int n4) {
    const int stride = gridDim.x * blockDim.x;
    for (int i = blockIdx.x * blockDim.x + threadIdx.x; i < n4; i += stride) {
        float4 v = src[i];
        half4 o = { (half_t)v.x, (half_t)v.y, (half_t)v.z, (half_t)v.w };
        dst[i] = o;
    }
}

extern "C" void kernel_launch(void* const* d_in, const int* in_sizes, int n_in,
                              void* d_out, int out_size, void* d_ws, size_t ws_size,
                              hipStream_t stream) {
    const float* h  = (const float*)d_in[0];
    const float* s  = (const float*)d_in[1];
    const float* Wh = (const float*)d_in[2];
    const float* bh = (const float*)d_in[3];
    const float* Ws = (const float*)d_in[4];
    const float* bs = (const float*)d_in[5];

    const long MB = 16384;   // B*TH
    const long D  = 1024;

    // workspace carve (~164 MB); h16/s16 region reused for f32 scores
    char* w = (char*)d_ws;
    half_t* h16 = (half_t*)w;  w += MB * D * 2;    // 32MB
    half_t* s16 = (half_t*)w;  w += MB * D * 2;    // 32MB
    float*  sc  = (float*)h16;                     // scores alias (64MB over h16+s16)
    half_t* Wh16 = (half_t*)w;  w += D * D * 2;
    half_t* Ws16 = (half_t*)w;  w += D * D * 2;
    half_t* hp16 = (half_t*)w;  w += MB * D * 2;   // [16384][1024]
    half_t* sp16 = (half_t*)w;  w += MB * D * 2;
    half_t* hpT  = (half_t*)w;  w += MB * D * 2;   // [16][o][t]

    hipFuncSetAttribute(reinterpret_cast<const void*>(&gemm256<0,1,1>),
                        hipFuncAttributeMaxDynamicSharedMemorySize, 131072);
    hipFuncSetAttribute(reinterpret_cast<const void*>(&gemm256<0,1,0>),
                        hipFuncAttributeMaxDynamicSharedMemorySize, 131072);
    hipFuncSetAttribute(reinterpret_cast<const void*>(&gemm256<1,0,0>),
                        hipFuncAttributeMaxDynamicSharedMemorySize, 131072);

    cvt_f16<<<512,  256, 0, stream>>>((const float4*)Wh, (half4*)Wh16, (int)(D * D / 4));
    cvt_f16<<<512,  256, 0, stream>>>((const float4*)Ws, (half4*)Ws16, (int)(D * D / 4));
    cvt_f16<<<2048, 256, 0, stream>>>((const float4*)h,  (half4*)h16,  (int)(MB * D / 4));
    cvt_f16<<<2048, 256, 0, stream>>>((const float4*)s,  (half4*)s16,  (int)(MB * D / 4));

    // GEMM1: hp = h*Wh^T + bh (fp16 + per-batch transposed copy)
    gemm256<0,1,1><<<dim3(64, 4, 1), 512, 131072, stream>>>(
        h16, Wh16, bh, nullptr, hp16, hpT, 1024, 1024, 1024, 0, 0, 0, 0);
    // GEMM2: sp = s*Ws^T + bs (fp16)
    gemm256<0,1,0><<<dim3(64, 4, 1), 512, 131072, stream>>>(
        s16, Ws16, bs, nullptr, sp16, nullptr, 1024, 1024, 1024, 0, 0, 0, 0);
    // GEMM3: scores[b] = hp_b * sp_b^T (f32, overlays dead h16/s16 region)
    gemm256<1,0,0><<<dim3(4, 4, 16), 512, 131072, stream>>>(
        hp16, sp16, nullptr, sc, nullptr, nullptr, 1024, 1024, 1024,
        1048576L, 1048576L, 1048576L, 1024);
    // softmax over j, fp16 probs written in place (row stride 2048 halves)
    softmax_inplace<<<16384, 256, 0, stream>>>(sc);
    // GEMM4: out[b] = probs_b * hpT_b^T (f32 -> d_out)
    gemm256<1,0,0><<<dim3(4, 4, 16), 512, 131072, stream>>>(
        (const half_t*)sc, hpT, nullptr, (float*)d_out, nullptr, nullptr,
        2048, 1024, 1024, 2097152L, 1048576L, 1048576L, 1024);
}

// Round 8
// 238.666 us; speedup vs baseline: 1.0872x; 1.0872x over previous
//
#include <hip/hip_runtime.h>
#include <hip/hip_bf16.h>
#include <stdint.h>

// B=16, TH=TS=HS=WS=1024
// res[b,i,o] = sum_j softmax_j(hp[b,i,:].sp[b,j,:]) * hp[b,j,o]
// hp = h*Wh^T + bh ; sp = s*Ws^T + bs
// fp16 operands, f32 MFMA accum. 256^2 8-phase GEMM. Barriers are inline-asm
// (invisible to the waitcnt pass) so the compiler cannot insert vmcnt(0)
// drains against in-flight global_load_lds prefetches; our counted vmcnt(4)
// gate at q3 is the only VMEM wait in the steady-state loop.

typedef _Float16 half_t;
typedef __attribute__((ext_vector_type(8))) _Float16 half8;   // 4 VGPR
typedef __attribute__((ext_vector_type(4))) _Float16 half4;
typedef __attribute__((ext_vector_type(4))) float floatx4;

__device__ __forceinline__ void gl2lds16(const void* g, void* l) {
    __builtin_amdgcn_global_load_lds(
        (const __attribute__((address_space(1))) uint32_t*)(uintptr_t)g,
        (__attribute__((address_space(3))) uint32_t*)(uintptr_t)l,
        16, 0, 0);
}

// asm barrier -> wait LDS data -> fence MFMA hoisting (rule #18)
#define PH_MID() do { \
    asm volatile("s_barrier\n\ts_waitcnt lgkmcnt(0)" ::: "memory"); \
    __builtin_amdgcn_sched_barrier(0); } while (0)

#define PH_END() asm volatile("s_barrier" ::: "memory")

#define QUAD(mq, nq) do { \
    __builtin_amdgcn_s_setprio(1); \
    _Pragma("unroll") for (int mi = 0; mi < 4; ++mi) \
    _Pragma("unroll") for (int ni = 0; ni < 2; ++ni) \
    _Pragma("unroll") for (int ks = 0; ks < 2; ++ks) \
        acc[(mq)*4+mi][(nq)*2+ni] = __builtin_amdgcn_mfma_f32_16x16x32_f16( \
            aF[mi][ks], bF[nq][ni][ks], acc[(mq)*4+mi][(nq)*2+ni], 0, 0, 0); \
    __builtin_amdgcn_s_setprio(0); } while (0)

#define NT16 16   // K = 1024, BK = 64

// C[r][c] = sum_k A[r][k]*B[c][k] (+bias[c]); operands K-major (B^T GEMM), fp16.
// 256x256 tile, 8 waves (2Mx4N), per-wave 128x64, double-buffered 128KB LDS.
// Swizzle: rows are 128B (=32 banks); XOR byte bits 4-6 with row&7 (both-sides:
// pre-swizzled global src + swizzle folded into the 4 read base offsets).
template<int WF32, int WH16, int WH16T>
__global__ __launch_bounds__(512, 2) void gemm256(
    const half_t* __restrict__ A, const half_t* __restrict__ B,
    const float* __restrict__ bias,
    float* __restrict__ Cf, half_t* __restrict__ Ch, half_t* __restrict__ ChT,
    int lda, int ldb, int N,
    long aBatch, long bBatch, long cfBatch, int ldcf)
{
    extern __shared__ char smem[];   // [2][ A:32KB | B:32KB ] = 128KB

    const int tid  = threadIdx.x;
    const int wave = tid >> 6;
    const int lane = tid & 63;
    const int wr = wave >> 2;        // 0..1 -> rows wr*128..+127
    const int wc = wave & 3;         // 0..3 -> cols wc*64..+63
    const int lr = lane & 15, lg = lane >> 4;

    const long batch = blockIdx.z;
    const half_t* Ab = A + batch * aBatch;
    const half_t* Bb = B + batch * bBatch;
    const int row0 = blockIdx.x * 256;
    const int col0 = blockIdx.y * 256;

    floatx4 acc[8][4];
#pragma unroll
    for (int m = 0; m < 8; ++m)
#pragma unroll
        for (int n = 0; n < 4; ++n)
            acc[m][n] = (floatx4){0.f, 0.f, 0.f, 0.f};

    // hoisted stage source offsets (bytes, excl. kk*2) per (half,i):
    // off bits 7-9 = row&7; inverse-swizzle XOR into bits 4-6 (involution).
    long aOff[2][2], bOff[2][2];
#pragma unroll
    for (int hh = 0; hh < 2; ++hh)
#pragma unroll
        for (int i = 0; i < 2; ++i) {
            const int off = hh * 16384 + i * 8192 + tid * 16;
            const int e = off ^ (((off >> 7) & 7) << 4);
            const int r = e >> 7, cb = e & 127;     // 128B per tile row
            aOff[hh][i] = (long)(row0 + r) * (long)(lda * 2) + cb;
            bOff[hh][i] = (long)(col0 + r) * (long)(ldb * 2) + cb;
        }

    const int wave_s = __builtin_amdgcn_readfirstlane(wave);
    auto stageHalf = [&](int buf, int isA, int hh, int kk) {
#pragma unroll
        for (int i = 0; i < 2; ++i) {
            const char* g = (isA ? (const char*)Ab + aOff[hh][i]
                                 : (const char*)Bb + bOff[hh][i]) + (long)kk * 2;
            gl2lds16(g, smem + buf * 65536 + (isA ? 0 : 32768)
                          + hh * 16384 + i * 8192 + wave_s * 1024);
        }
    };

    // fragment-read bases (swizzle folded; mt/nt*2048 additive -> offset imm).
    // buf toggled by XOR 65536 once per K-tile.
    uint32_t aof0 = (uint32_t)((wr * 128 + lr) * 128 + ((lg * 16) ^ ((lr & 7) << 4)));
    uint32_t aof1 = (uint32_t)((wr * 128 + lr) * 128 + ((64 + lg * 16) ^ ((lr & 7) << 4)));
    uint32_t bof0 = (uint32_t)(32768 + (wc * 64 + lr) * 128 + ((lg * 16) ^ ((lr & 7) << 4)));
    uint32_t bof1 = (uint32_t)(32768 + (wc * 64 + lr) * 128 + ((64 + lg * 16) ^ ((lr & 7) << 4)));

    // ---- prologue: tile0 full + tile1 B halves; retire tile0, barrier.
    stageHalf(0, 0, 0, 0);   stageHalf(0, 0, 1, 0);     // tile0 B0,B1
    stageHalf(0, 1, 0, 0);   stageHalf(0, 1, 1, 0);     // tile0 A0,A1
    stageHalf(1, 0, 0, 64);  stageHalf(1, 0, 1, 64);    // tile1 B0,B1
    asm volatile("s_waitcnt vmcnt(4)" ::: "memory");
    asm volatile("s_barrier" ::: "memory");

    half8 aF[4][2];          // current A m-quadrant (4 m-tiles x 2 ksub)
    half8 bF[2][2][2];       // both B n-quadrants (persist q0->q3)

    for (int t = 0; t < NT16; ++t) {
        // ---- q0: read aF-low + bF[0]; stage A0(t+1) -> buf^1
#pragma unroll
        for (int mi = 0; mi < 4; ++mi) {
            aF[mi][0] = *(const half8*)(smem + aof0 + mi * 2048);
            aF[mi][1] = *(const half8*)(smem + aof1 + mi * 2048);
        }
#pragma unroll
        for (int ni = 0; ni < 2; ++ni) {
            bF[0][ni][0] = *(const half8*)(smem + bof0 + ni * 2048);
            bF[0][ni][1] = *(const half8*)(smem + bof1 + ni * 2048);
        }
        if (t + 1 < NT16) stageHalf((t & 1) ^ 1, 1, 0, (t + 1) * 64);
        PH_MID();
        QUAD(0, 0);
        PH_END();

        // ---- q1: read bF[1]; stage A1(t+1) -> buf^1
#pragma unroll
        for (int ni = 0; ni < 2; ++ni) {
            bF[1][ni][0] = *(const half8*)(smem + bof0 + (2 + ni) * 2048);
            bF[1][ni][1] = *(const half8*)(smem + bof1 + (2 + ni) * 2048);
        }
        if (t + 1 < NT16) stageHalf((t & 1) ^ 1, 1, 1, (t + 1) * 64);
        PH_MID();
        QUAD(0, 1);
        PH_END();

        // ---- q2: read aF-high; stage B0(t+2) -> buf cur
#pragma unroll
        for (int mi = 0; mi < 4; ++mi) {
            aF[mi][0] = *(const half8*)(smem + aof0 + (4 + mi) * 2048);
            aF[mi][1] = *(const half8*)(smem + aof1 + (4 + mi) * 2048);
        }
        if (t + 2 < NT16) stageHalf(t & 1, 0, 0, (t + 2) * 64);
        PH_MID();
        QUAD(1, 1);
        PH_END();

        // ---- q3: stage B1(t+2); counted gate vmcnt(4): retires B(t+1)+A(t+1),
        //      leaves B(t+2)'s 4 insts in flight.
        if (t + 2 < NT16) {
            stageHalf(t & 1, 0, 1, (t + 2) * 64);
            asm volatile("s_waitcnt vmcnt(4)" ::: "memory");
        } else {
            asm volatile("s_waitcnt vmcnt(0)" ::: "memory");   // tail drain
        }
        PH_MID();
        QUAD(1, 0);
        PH_END();

        aof0 ^= 65536; aof1 ^= 65536; bof0 ^= 65536; bof1 ^= 65536;
    }

    // ---- epilogue: transpose acc through LDS (free after last PH_END) for
    // coalesced 16B stores. Per-wave disjoint 16x36-f32 scratch (pad->2-way max).
    {
        float* wlds = (float*)(smem + wave * 2304);   // 16*36*4 = 2304B
        float bv[4];
#pragma unroll
        for (int n = 0; n < 4; ++n)
            bv[n] = bias ? bias[col0 + wc * 64 + n * 16 + lr] : 0.f;
        const int er = lane >> 2, ec = lane & 3;     // hp/f32 read-back coords
        const int oc = lane >> 1, tc = lane & 1;     // hpT read-back coords
#pragma unroll
        for (int m = 0; m < 8; ++m) {
#pragma unroll
            for (int np = 0; np < 2; ++np) {
                // write 16 rows x 32 cols f32 (row=lg*4+j, col=n2*16+lr)
#pragma unroll
                for (int n2 = 0; n2 < 2; ++n2)
#pragma unroll
                    for (int j = 0; j < 4; ++j)
                        wlds[(lg * 4 + j) * 36 + n2 * 16 + lr] =
                            acc[m][np * 2 + n2][j] + bv[np * 2 + n2];
                const int grow = row0 + wr * 128 + m * 16;
                const int gcol = col0 + wc * 64 + np * 32;
                float4 q0 = *(float4*)&wlds[er * 36 + ec * 8];
                float4 q1 = *(float4*)&wlds[er * 36 + ec * 8 + 4];
                if (WF32) {
                    float* p = Cf + batch * cfBatch + (long)(grow + er) * ldcf + gcol + ec * 8;
                    *(float4*)p = q0;
                    *(float4*)(p + 4) = q1;
                }
                if (WH16) {
                    half8 o = { (half_t)q0.x, (half_t)q0.y, (half_t)q0.z, (half_t)q0.w,
                                (half_t)q1.x, (half_t)q1.y, (half_t)q1.z, (half_t)q1.w };
                    *(half8*)&Ch[(long)(grow + er) * N + gcol + ec * 8] = o;
                }
                if (WH16T) {
                    float tv[8];
#pragma unroll
                    for (int k = 0; k < 8; ++k)
                        tv[k] = wlds[(tc * 8 + k) * 36 + oc];
                    half8 o = { (half_t)tv[0], (half_t)tv[1], (half_t)tv[2], (half_t)tv[3],
                                (half_t)tv[4], (half_t)tv[5], (half_t)tv[6], (half_t)tv[7] };
                    const int gt = grow + tc * 8;
                    *(half8*)&ChT[(long)(gt >> 10) * 1048576
                                  + (long)(gcol + oc) * 1024 + (gt & 1023)] = o;
                }
                __builtin_amdgcn_s_waitcnt(0);   // drain LDS before next round's overwrite
            }
        }
    }
}

// In-place: reads f32 row (1024), writes fp16 probabilities over its own first half.
__global__ void softmax_inplace(float* __restrict__ S) {
    const long r = blockIdx.x;
    float* row = S + r * 1024;
    const int tid = threadIdx.x;
    const int wave = tid >> 6, lane = tid & 63;

    float4 v = ((const float4*)row)[tid];
    float mx = fmaxf(fmaxf(v.x, v.y), fmaxf(v.z, v.w));
#pragma unroll
    for (int off = 32; off > 0; off >>= 1)
        mx = fmaxf(mx, __shfl_xor(mx, off));
    __shared__ float rmx[4], rsm[4];
    if (lane == 0) rmx[wave] = mx;
    __syncthreads();
    mx = fmaxf(fmaxf(rmx[0], rmx[1]), fmaxf(rmx[2], rmx[3]));

    float e0 = __expf(v.x - mx), e1 = __expf(v.y - mx);
    float e2 = __expf(v.z - mx), e3 = __expf(v.w - mx);
    float s = e0 + e1 + e2 + e3;
#pragma unroll
    for (int off = 32; off > 0; off >>= 1)
        s += __shfl_xor(s, off);
    if (lane == 0) rsm[wave] = s;
    __syncthreads();
    s = rsm[0] + rsm[1] + rsm[2] + rsm[3];

    const float inv = 1.0f / s;
    half4 o = { (half_t)(e0 * inv), (half_t)(e1 * inv), (half_t)(e2 * inv), (half_t)(e3 * inv) };
    ((half4*)((half_t*)S + r * 2048))[tid] = o;
}

__global__ void cvt_f16(const float4* __restrict__ src, half4* __restrict__ dst, int n4) {
    const int stride = gridDim.x * blockDim.x;
    for (int i = blockIdx.x * blockDim.x + threadIdx.x; i < n4; i += stride) {
        float4 v = src[i];
        half4 o = { (half_t)v.x, (half_t)v.y, (half_t)v.z, (half_t)v.w };
        dst[i] = o;
    }
}

extern "C" void kernel_launch(void* const* d_in, const int* in_sizes, int n_in,
                              void* d_out, int out_size, void* d_ws, size_t ws_size,
                              hipStream_t stream) {
    const float* h  = (const float*)d_in[0];
    const float* s  = (const float*)d_in[1];
    const float* Wh = (const float*)d_in[2];
    const float* bh = (const float*)d_in[3];
    const float* Ws = (const float*)d_in[4];
    const float* bs = (const float*)d_in[5];

    const long MB = 16384;   // B*TH
    const long D  = 1024;

    // workspace carve (~164 MB); h16/s16 region reused for f32 scores
    char* w = (char*)d_ws;
    half_t* h16 = (half_t*)w;  w += MB * D * 2;    // 32MB
    half_t* s16 = (half_t*)w;  w += MB * D * 2;    // 32MB
    float*  sc  = (float*)h16;                     // scores alias (64MB over h16+s16)
    half_t* Wh16 = (half_t*)w;  w += D * D * 2;
    half_t* Ws16 = (half_t*)w;  w += D * D * 2;
    half_t* hp16 = (half_t*)w;  w += MB * D * 2;   // [16384][1024]
    half_t* sp16 = (half_t*)w;  w += MB * D * 2;
    half_t* hpT  = (half_t*)w;  w += MB * D * 2;   // [16][o][t]

    hipFuncSetAttribute(reinterpret_cast<const void*>(&gemm256<0,1,1>),
                        hipFuncAttributeMaxDynamicSharedMemorySize, 131072);
    hipFuncSetAttribute(reinterpret_cast<const void*>(&gemm256<0,1,0>),
                        hipFuncAttributeMaxDynamicSharedMemorySize, 131072);
    hipFuncSetAttribute(reinterpret_cast<const void*>(&gemm256<1,0,0>),
                        hipFuncAttributeMaxDynamicSharedMemorySize, 131072);

    cvt_f16<<<512,  256, 0, stream>>>((const float4*)Wh, (half4*)Wh16, (int)(D * D / 4));
    cvt_f16<<<512,  256, 0, stream>>>((const float4*)Ws, (half4*)Ws16, (int)(D * D / 4));
    cvt_f16<<<2048, 256, 0, stream>>>((const float4*)h,  (half4*)h16,  (int)(MB * D / 4));
    cvt_f16<<<2048, 256, 0, stream>>>((const float4*)s,  (half4*)s16,  (int)(MB * D / 4));

    // GEMM1: hp = h*Wh^T + bh (fp16 + per-batch transposed copy)
    gemm256<0,1,1><<<dim3(64, 4, 1), 512, 131072, stream>>>(
        h16, Wh16, bh, nullptr, hp16, hpT, 1024, 1024, 1024, 0, 0, 0, 0);
    // GEMM2: sp = s*Ws^T + bs (fp16)
    gemm256<0,1,0><<<dim3(64, 4, 1), 512, 131072, stream>>>(
        s16, Ws16, bs, nullptr, sp16, nullptr, 1024, 1024, 1024, 0, 0, 0, 0);
    // GEMM3: scores[b] = hp_b * sp_b^T (f32, overlays dead h16/s16 region)
    gemm256<1,0,0><<<dim3(4, 4, 16), 512, 131072, stream>>>(
        hp16, sp16, nullptr, sc, nullptr, nullptr, 1024, 1024, 1024,
        1048576L, 1048576L, 1048576L, 1024);
    // softmax over j, fp16 probs written in place (row stride 2048 halves)
    softmax_inplace<<<16384, 256, 0, stream>>>(sc);
    // GEMM4: out[b] = probs_b * hpT_b^T (f32 -> d_out)
    gemm256<1,0,0><<<dim3(4, 4, 16), 512, 131072, stream>>>(
        (const half_t*)sc, hpT, nullptr, (float*)d_out, nullptr, nullptr,
        2048, 1024, 1024, 2097152L, 1048576L, 1048576L, 1024);
}

// Round 9
// 236.771 us; speedup vs baseline: 1.0959x; 1.0080x over previous
//
#include <hip/hip_runtime.h>
#include <hip/hip_bf16.h>
#include <stdint.h>

// B=16, TH=TS=HS=WS=1024
// res[b,i,o] = sum_j softmax_j(hp[b,i,:].sp[b,j,:]) * hp[b,j,o]
// hp = h*Wh^T + bh ; sp = s*Ws^T + bs
// fp16 operands, f32 MFMA accum. 256^2 GEMM, guide-verbatim minimum-2-phase
// loop (T3 recipe): STAGE(t+1) issued first, all reads+MFMA of tile t, ONE
// __syncthreads per K-step. Reference for this shape: 682 TF (m230-V0).

typedef _Float16 half_t;
typedef __attribute__((ext_vector_type(8))) _Float16 half8;   // 4 VGPR
typedef __attribute__((ext_vector_type(4))) _Float16 half4;
typedef __attribute__((ext_vector_type(4))) float floatx4;

__device__ __forceinline__ void gl2lds16(const void* g, void* l) {
    __builtin_amdgcn_global_load_lds(
        (const __attribute__((address_space(1))) uint32_t*)(uintptr_t)g,
        (__attribute__((address_space(3))) uint32_t*)(uintptr_t)l,
        16, 0, 0);
}

#define NT16 16   // K = 1024, BK = 64

// C[r][c] = sum_k A[r][k]*B[c][k] (+bias[c]); operands K-major (B^T GEMM), fp16.
// 256x256 tile, 8 waves (2Mx4N), per-wave 128x64, double-buffered 128KB LDS.
// Swizzle: rows are 128B (=32 banks); XOR byte bits 4-6 with row&7 (both-sides:
// pre-swizzled global src + swizzle folded into the 4 read base offsets).
template<int WF32, int WH16, int WH16T>
__global__ __launch_bounds__(512, 2) void gemm256(
    const half_t* __restrict__ A, const half_t* __restrict__ B,
    const float* __restrict__ bias,
    float* __restrict__ Cf, half_t* __restrict__ Ch, half_t* __restrict__ ChT,
    int lda, int ldb, int N,
    long aBatch, long bBatch, long cfBatch, int ldcf)
{
    extern __shared__ char smem[];   // [2][ A:32KB | B:32KB ] = 128KB

    const int tid  = threadIdx.x;
    const int wave = tid >> 6;
    const int lane = tid & 63;
    const int wr = wave >> 2;        // 0..1 -> rows wr*128..+127
    const int wc = wave & 3;         // 0..3 -> cols wc*64..+63
    const int lr = lane & 15, lg = lane >> 4;

    const long batch = blockIdx.z;
    const half_t* Ab = A + batch * aBatch;
    const half_t* Bb = B + batch * bBatch;
    const int row0 = blockIdx.x * 256;
    const int col0 = blockIdx.y * 256;

    floatx4 acc[8][4];
#pragma unroll
    for (int m = 0; m < 8; ++m)
#pragma unroll
        for (int n = 0; n < 4; ++n)
            acc[m][n] = (floatx4){0.f, 0.f, 0.f, 0.f};

    // hoisted stage source offsets (bytes, excl. kk*2) per (half,i):
    // off bits 7-9 = row&7; inverse-swizzle XOR into bits 4-6 (involution).
    long aOff[2][2], bOff[2][2];
#pragma unroll
    for (int hh = 0; hh < 2; ++hh)
#pragma unroll
        for (int i = 0; i < 2; ++i) {
            const int off = hh * 16384 + i * 8192 + tid * 16;
            const int e = off ^ (((off >> 7) & 7) << 4);
            const int r = e >> 7, cb = e & 127;     // 128B per tile row
            aOff[hh][i] = (long)(row0 + r) * (long)(lda * 2) + cb;
            bOff[hh][i] = (long)(col0 + r) * (long)(ldb * 2) + cb;
        }

    const int wave_s = __builtin_amdgcn_readfirstlane(wave);
    auto stageHalf = [&](int buf, int isA, int hh, int kk) {
#pragma unroll
        for (int i = 0; i < 2; ++i) {
            const char* g = (isA ? (const char*)Ab + aOff[hh][i]
                                 : (const char*)Bb + bOff[hh][i]) + (long)kk * 2;
            gl2lds16(g, smem + buf * 65536 + (isA ? 0 : 32768)
                          + hh * 16384 + i * 8192 + wave_s * 1024);
        }
    };

    // fragment-read bases (swizzle folded; mt/nt*2048 additive -> offset imm).
    uint32_t aof0 = (uint32_t)((wr * 128 + lr) * 128 + ((lg * 16) ^ ((lr & 7) << 4)));
    uint32_t aof1 = (uint32_t)((wr * 128 + lr) * 128 + ((64 + lg * 16) ^ ((lr & 7) << 4)));
    uint32_t bof0 = (uint32_t)(32768 + (wc * 64 + lr) * 128 + ((lg * 16) ^ ((lr & 7) << 4)));
    uint32_t bof1 = (uint32_t)(32768 + (wc * 64 + lr) * 128 + ((64 + lg * 16) ^ ((lr & 7) << 4)));

    // ---- prologue: stage tile 0 into buf0 (8 gl2lds/thread), sync.
    stageHalf(0, 1, 0, 0);  stageHalf(0, 1, 1, 0);    // A0,A1
    stageHalf(0, 0, 0, 0);  stageHalf(0, 0, 1, 0);    // B0,B1
    __syncthreads();

    for (int t = 0; t < NT16; ++t) {
        // (1) STAGE tile t+1 into buf^1 — issued FIRST so the end-of-step
        //     drain is covered by the reads+MFMA below (T3 minimum recipe).
        if (t + 1 < NT16) {
            const int nxt = (t & 1) ^ 1;
            const int k1 = (t + 1) * 64;
            stageHalf(nxt, 1, 0, k1);  stageHalf(nxt, 1, 1, k1);
            stageHalf(nxt, 0, 0, k1);  stageHalf(nxt, 0, 1, k1);
        }

        // (2) reads + MFMA of tile t, in two 32-MFMA halves (caps VGPR)
        half8 aF[4][2], bF[4][2];
#pragma unroll
        for (int ni = 0; ni < 4; ++ni) {
            bF[ni][0] = *(const half8*)(smem + bof0 + ni * 2048);
            bF[ni][1] = *(const half8*)(smem + bof1 + ni * 2048);
        }
#pragma unroll
        for (int mi = 0; mi < 4; ++mi) {
            aF[mi][0] = *(const half8*)(smem + aof0 + mi * 2048);
            aF[mi][1] = *(const half8*)(smem + aof1 + mi * 2048);
        }
#pragma unroll
        for (int mi = 0; mi < 4; ++mi)
#pragma unroll
            for (int ni = 0; ni < 4; ++ni)
#pragma unroll
                for (int ks = 0; ks < 2; ++ks)
                    acc[mi][ni] = __builtin_amdgcn_mfma_f32_16x16x32_f16(
                        aF[mi][ks], bF[ni][ks], acc[mi][ni], 0, 0, 0);
#pragma unroll
        for (int mi = 0; mi < 4; ++mi) {
            aF[mi][0] = *(const half8*)(smem + aof0 + (4 + mi) * 2048);
            aF[mi][1] = *(const half8*)(smem + aof1 + (4 + mi) * 2048);
        }
#pragma unroll
        for (int mi = 0; mi < 4; ++mi)
#pragma unroll
            for (int ni = 0; ni < 4; ++ni)
#pragma unroll
                for (int ks = 0; ks < 2; ++ks)
                    acc[4 + mi][ni] = __builtin_amdgcn_mfma_f32_16x16x32_f16(
                        aF[mi][ks], bF[ni][ks], acc[4 + mi][ni], 0, 0, 0);

        // (3) one barrier per K-step (compiler adds the vmcnt/lgkm drain here)
        __syncthreads();
        aof0 ^= 65536; aof1 ^= 65536; bof0 ^= 65536; bof1 ^= 65536;
    }

    // ---- epilogue: transpose acc through LDS for coalesced 16B stores.
    {
        float* wlds = (float*)(smem + wave * 2304);   // per-wave 16x36 f32
        float bv[4];
#pragma unroll
        for (int n = 0; n < 4; ++n)
            bv[n] = bias ? bias[col0 + wc * 64 + n * 16 + lr] : 0.f;
        const int er = lane >> 2, ec = lane & 3;     // row-major read-back coords
        const int oc = lane >> 1, tc = lane & 1;     // transposed read-back coords
#pragma unroll
        for (int m = 0; m < 8; ++m) {
#pragma unroll
            for (int np = 0; np < 2; ++np) {
#pragma unroll
                for (int n2 = 0; n2 < 2; ++n2)
#pragma unroll
                    for (int j = 0; j < 4; ++j)
                        wlds[(lg * 4 + j) * 36 + n2 * 16 + lr] =
                            acc[m][np * 2 + n2][j] + bv[np * 2 + n2];
                const int grow = row0 + wr * 128 + m * 16;
                const int gcol = col0 + wc * 64 + np * 32;
                float4 q0 = *(float4*)&wlds[er * 36 + ec * 8];
                float4 q1 = *(float4*)&wlds[er * 36 + ec * 8 + 4];
                if (WF32) {
                    float* p = Cf + batch * cfBatch + (long)(grow + er) * ldcf + gcol + ec * 8;
                    *(float4*)p = q0;
                    *(float4*)(p + 4) = q1;
                }
                if (WH16) {
                    half8 o = { (half_t)q0.x, (half_t)q0.y, (half_t)q0.z, (half_t)q0.w,
                                (half_t)q1.x, (half_t)q1.y, (half_t)q1.z, (half_t)q1.w };
                    *(half8*)&Ch[(long)(grow + er) * N + gcol + ec * 8] = o;
                }
                if (WH16T) {
                    float tv[8];
#pragma unroll
                    for (int k = 0; k < 8; ++k)
                        tv[k] = wlds[(tc * 8 + k) * 36 + oc];
                    half8 o = { (half_t)tv[0], (half_t)tv[1], (half_t)tv[2], (half_t)tv[3],
                                (half_t)tv[4], (half_t)tv[5], (half_t)tv[6], (half_t)tv[7] };
                    const int gt = grow + tc * 8;
                    *(half8*)&ChT[(long)(gt >> 10) * 1048576
                                  + (long)(gcol + oc) * 1024 + (gt & 1023)] = o;
                }
                __builtin_amdgcn_s_waitcnt(0);   // drain before next overwrite of wlds
            }
        }
    }
}

// In-place: reads f32 row (1024), writes fp16 probabilities over its own first half.
__global__ void softmax_inplace(float* __restrict__ S) {
    const long r = blockIdx.x;
    float* row = S + r * 1024;
    const int tid = threadIdx.x;
    const int wave = tid >> 6, lane = tid & 63;

    float4 v = ((const float4*)row)[tid];
    float mx = fmaxf(fmaxf(v.x, v.y), fmaxf(v.z, v.w));
#pragma unroll
    for (int off = 32; off > 0; off >>= 1)
        mx = fmaxf(mx, __shfl_xor(mx, off));
    __shared__ float rmx[4], rsm[4];
    if (lane == 0) rmx[wave] = mx;
    __syncthreads();
    mx = fmaxf(fmaxf(rmx[0], rmx[1]), fmaxf(rmx[2], rmx[3]));

    float e0 = __expf(v.x - mx), e1 = __expf(v.y - mx);
    float e2 = __expf(v.z - mx), e3 = __expf(v.w - mx);
    float s = e0 + e1 + e2 + e3;
#pragma unroll
    for (int off = 32; off > 0; off >>= 1)
        s += __shfl_xor(s, off);
    if (lane == 0) rsm[wave] = s;
    __syncthreads();
    s = rsm[0] + rsm[1] + rsm[2] + rsm[3];

    const float inv = 1.0f / s;
    half4 o = { (half_t)(e0 * inv), (half_t)(e1 * inv), (half_t)(e2 * inv), (half_t)(e3 * inv) };
    ((half4*)((half_t*)S + r * 2048))[tid] = o;
}

__global__ void cvt_f16(const float4* __restrict__ src, half4* __restrict__ dst, int n4) {
    const int stride = gridDim.x * blockDim.x;
    for (int i = blockIdx.x * blockDim.x + threadIdx.x; i < n4; i += stride) {
        float4 v = src[i];
        half4 o = { (half_t)v.x, (half_t)v.y, (half_t)v.z, (half_t)v.w };
        dst[i] = o;
    }
}

extern "C" void kernel_launch(void* const* d_in, const int* in_sizes, int n_in,
                              void* d_out, int out_size, void* d_ws, size_t ws_size,
                              hipStream_t stream) {
    const float* h  = (const float*)d_in[0];
    const float* s  = (const float*)d_in[1];
    const float* Wh = (const float*)d_in[2];
    const float* bh = (const float*)d_in[3];
    const float* Ws = (const float*)d_in[4];
    const float* bs = (const float*)d_in[5];

    const long MB = 16384;   // B*TH
    const long D  = 1024;

    // workspace carve (~164 MB); h16/s16 region reused for f32 scores
    char* w = (char*)d_ws;
    half_t* h16 = (half_t*)w;  w += MB * D * 2;    // 32MB
    half_t* s16 = (half_t*)w;  w += MB * D * 2;    // 32MB
    float*  sc  = (float*)h16;                     // scores alias (64MB over h16+s16)
    half_t* Wh16 = (half_t*)w;  w += D * D * 2;
    half_t* Ws16 = (half_t*)w;  w += D * D * 2;
    half_t* hp16 = (half_t*)w;  w += MB * D * 2;   // [16384][1024]
    half_t* sp16 = (half_t*)w;  w += MB * D * 2;
    half_t* hpT  = (half_t*)w;  w += MB * D * 2;   // [16][o][t]

    hipFuncSetAttribute(reinterpret_cast<const void*>(&gemm256<0,1,1>),
                        hipFuncAttributeMaxDynamicSharedMemorySize, 131072);
    hipFuncSetAttribute(reinterpret_cast<const void*>(&gemm256<0,1,0>),
                        hipFuncAttributeMaxDynamicSharedMemorySize, 131072);
    hipFuncSetAttribute(reinterpret_cast<const void*>(&gemm256<1,0,0>),
                        hipFuncAttributeMaxDynamicSharedMemorySize, 131072);

    cvt_f16<<<512,  256, 0, stream>>>((const float4*)Wh, (half4*)Wh16, (int)(D * D / 4));
    cvt_f16<<<512,  256, 0, stream>>>((const float4*)Ws, (half4*)Ws16, (int)(D * D / 4));
    cvt_f16<<<2048, 256, 0, stream>>>((const float4*)h,  (half4*)h16,  (int)(MB * D / 4));
    cvt_f16<<<2048, 256, 0, stream>>>((const float4*)s,  (half4*)s16,  (int)(MB * D / 4));

    // GEMM1: hp = h*Wh^T + bh (fp16 + per-batch transposed copy)
    gemm256<0,1,1><<<dim3(64, 4, 1), 512, 131072, stream>>>(
        h16, Wh16, bh, nullptr, hp16, hpT, 1024, 1024, 1024, 0, 0, 0, 0);
    // GEMM2: sp = s*Ws^T + bs (fp16)
    gemm256<0,1,0><<<dim3(64, 4, 1), 512, 131072, stream>>>(
        s16, Ws16, bs, nullptr, sp16, nullptr, 1024, 1024, 1024, 0, 0, 0, 0);
    // GEMM3: scores[b] = hp_b * sp_b^T (f32, overlays dead h16/s16 region)
    gemm256<1,0,0><<<dim3(4, 4, 16), 512, 131072, stream>>>(
        hp16, sp16, nullptr, sc, nullptr, nullptr, 1024, 1024, 1024,
        1048576L, 1048576L, 1048576L, 1024);
    // softmax over j, fp16 probs written in place (row stride 2048 halves)
    softmax_inplace<<<16384, 256, 0, stream>>>(sc);
    // GEMM4: out[b] = probs_b * hpT_b^T (f32 -> d_out)
    gemm256<1,0,0><<<dim3(4, 4, 16), 512, 131072, stream>>>(
        (const half_t*)sc, hpT, nullptr, (float*)d_out, nullptr, nullptr,
        2048, 1024, 1024, 2097152L, 1048576L, 1048576L, 1024);
}

// Round 11
// 223.209 us; speedup vs baseline: 1.1625x; 1.0608x over previous
//
#include <hip/hip_runtime.h>
#include <hip/hip_bf16.h>
#include <stdint.h>

// B=16, TH=TS=HS=WS=1024
// res[b,i,o] = sum_j softmax_j(hp[b,i,:].sp[b,j,:]) * hp[b,j,o]
// hp = h*Wh^T + bh ; sp = s*Ws^T + bs
// fp16 operands, f32 MFMA accum. 256^2 GEMM, minimum-2-phase loop.
// R11 == R10 with the GEMM4 launch-arg count fixed:
// (a) GEMM1/2 stage A directly from f32 (fused cvt, reg-staged with swizzled
// ds_write); (b) GEMM3/4 use bijective XCD-batch swizzle so each batch's 16
// blocks share one XCD L2 (panel fetched once).

typedef _Float16 half_t;
typedef __attribute__((ext_vector_type(8))) _Float16 half8;   // 4 VGPR
typedef __attribute__((ext_vector_type(4))) _Float16 half4;
typedef __attribute__((ext_vector_type(4))) float floatx4;

__device__ __forceinline__ void gl2lds16(const void* g, void* l) {
    __builtin_amdgcn_global_load_lds(
        (const __attribute__((address_space(1))) uint32_t*)(uintptr_t)g,
        (__attribute__((address_space(3))) uint32_t*)(uintptr_t)l,
        16, 0, 0);
}

#define NT16 16   // K = 1024, BK = 64

// C[r][c] = sum_k A[r][k]*B[c][k] (+bias[c]); operands K-major (B^T GEMM).
// 256x256 tile, 8 waves (2Mx4N), per-wave 128x64, double-buffered 128KB LDS.
// Swizzle: rows are 128B (=32 banks); XOR byte bits 4-6 with row&7.
// RSA: A staged from f32 global (load->cvt->swizzled ds_write).
// SWZ: grid must be (4,4,16); batch remapped so all 16 tiles of a batch land
// on one XCD (linear dispatch id round-robins XCDs).
template<int WF32, int WH16, int WH16T, int RSA, int SWZ>
__global__ __launch_bounds__(512, 2) void gemm256(
    const half_t* __restrict__ A, const float* __restrict__ A32,
    const half_t* __restrict__ B,
    const float* __restrict__ bias,
    float* __restrict__ Cf, half_t* __restrict__ Ch, half_t* __restrict__ ChT,
    int lda, int ldb, int N,
    long aBatch, long bBatch, long cfBatch, int ldcf)
{
    extern __shared__ char smem[];   // [2][ A:32KB | B:32KB ] = 128KB

    const int tid  = threadIdx.x;
    const int wave = tid >> 6;
    const int lane = tid & 63;
    const int wr = wave >> 2;        // 0..1 -> rows wr*128..+127
    const int wc = wave & 3;         // 0..3 -> cols wc*64..+63
    const int lr = lane & 15, lg = lane >> 4;

    long batch; int row0, col0;
    if constexpr (SWZ) {
        const int lin = blockIdx.x + (blockIdx.y << 2) + (blockIdx.z << 4);
        const int xcd = lin & 7, per = lin >> 3;          // 32 blocks per XCD
        batch = (xcd << 1) | (per >> 4);                  // 2 batches per XCD
        const int wt = per & 15;
        row0 = (wt & 3) * 256;
        col0 = (wt >> 2) * 256;
    } else {
        batch = blockIdx.z;
        row0 = blockIdx.x * 256;
        col0 = blockIdx.y * 256;
    }

    const half_t* Bb = B + batch * bBatch;

    floatx4 acc[8][4];
#pragma unroll
    for (int m = 0; m < 8; ++m)
#pragma unroll
        for (int n = 0; n < 4; ++n)
            acc[m][n] = (floatx4){0.f, 0.f, 0.f, 0.f};

    // hoisted B stage source offsets (pre-swizzled global src for gl2lds):
    long bOff[2][2];
    long aOffG[2][2];                 // A gl2lds path (non-RSA)
#pragma unroll
    for (int hh = 0; hh < 2; ++hh)
#pragma unroll
        for (int i = 0; i < 2; ++i) {
            const int off = hh * 16384 + i * 8192 + tid * 16;
            const int e = off ^ (((off >> 7) & 7) << 4);
            const int r = e >> 7, cb = e & 127;
            bOff[hh][i] = (long)(col0 + r) * (long)(ldb * 2) + cb;
            if constexpr (!RSA)
                aOffG[hh][i] = (long)(row0 + r) * (long)(lda * 2) + cb;
        }

    const int wave_s = __builtin_amdgcn_readfirstlane(wave);
    auto stageB = [&](int buf, int kk) {
#pragma unroll
        for (int hh = 0; hh < 2; ++hh)
#pragma unroll
            for (int i = 0; i < 2; ++i)
                gl2lds16((const char*)Bb + bOff[hh][i] + (long)kk * 2,
                         smem + buf * 65536 + 32768 + hh * 16384 + i * 8192 + wave_s * 1024);
    };
    auto stageA16 = [&](int buf, int kk) {   // non-RSA: fp16 A via gl2lds
        const half_t* Ab = A + batch * aBatch;
#pragma unroll
        for (int hh = 0; hh < 2; ++hh)
#pragma unroll
            for (int i = 0; i < 2; ++i)
                gl2lds16((const char*)Ab + aOffG[hh][i] + (long)kk * 2,
                         smem + buf * 65536 + hh * 16384 + i * 8192 + wave_s * 1024);
    };

    // RSA chunk coords (4 chunks x 16B fp16 per thread)
    int rsaRow[4], rsaKb[4];
#pragma unroll
    for (int c = 0; c < 4; ++c) {
        const int off = c * 8192 + tid * 16;
        rsaRow[c] = off >> 7;
        rsaKb[c]  = off & 127;
    }

    // fragment-read bases (swizzle folded)
    uint32_t aof0 = (uint32_t)((wr * 128 + lr) * 128 + ((lg * 16) ^ ((lr & 7) << 4)));
    uint32_t aof1 = (uint32_t)((wr * 128 + lr) * 128 + ((64 + lg * 16) ^ ((lr & 7) << 4)));
    uint32_t bof0 = (uint32_t)(32768 + (wc * 64 + lr) * 128 + ((lg * 16) ^ ((lr & 7) << 4)));
    uint32_t bof1 = (uint32_t)(32768 + (wc * 64 + lr) * 128 + ((64 + lg * 16) ^ ((lr & 7) << 4)));

    // staging of A for RSA: load 8xfloat4 -> cvt -> 4x ds_write_b128 (swizzled)
    auto rsaLoad = [&](float4 (&fv)[4][2], int kk) {
#pragma unroll
        for (int c = 0; c < 4; ++c) {
            const float* src = A32 + batch * aBatch
                             + (long)(row0 + rsaRow[c]) * lda + kk + (rsaKb[c] >> 1);
            fv[c][0] = *(const float4*)src;
            fv[c][1] = *(const float4*)(src + 4);
        }
    };
    auto rsaWrite = [&](float4 (&fv)[4][2], int buf) {
#pragma unroll
        for (int c = 0; c < 4; ++c) {
            half8 o = { (half_t)fv[c][0].x, (half_t)fv[c][0].y, (half_t)fv[c][0].z, (half_t)fv[c][0].w,
                        (half_t)fv[c][1].x, (half_t)fv[c][1].y, (half_t)fv[c][1].z, (half_t)fv[c][1].w };
            *(half8*)(smem + buf * 65536 + rsaRow[c] * 128
                      + (rsaKb[c] ^ ((rsaRow[c] & 7) << 4))) = o;
        }
    };

    // ---- prologue: stage tile 0, sync.
    if constexpr (RSA) {
        float4 fv[4][2];
        rsaLoad(fv, 0);
        stageB(0, 0);
        rsaWrite(fv, 0);
    } else {
        stageA16(0, 0);
        stageB(0, 0);
    }
    __syncthreads();

    for (int t = 0; t < NT16; ++t) {
        const int nxt = (t & 1) ^ 1;
        const int k1 = (t + 1) * 64;

        // (1) issue next-tile staging loads first (T3 recipe)
        float4 fv[4][2];
        if (t + 1 < NT16) {
            if constexpr (RSA) {
                rsaLoad(fv, k1);     // f32 loads in flight; writes deferred below
                stageB(nxt, k1);
            } else {
                stageA16(nxt, k1);
                stageB(nxt, k1);
            }
        }

        // (2) ds_reads of tile t
        half8 aF[4][2], bF[4][2];
#pragma unroll
        for (int ni = 0; ni < 4; ++ni) {
            bF[ni][0] = *(const half8*)(smem + bof0 + ni * 2048);
            bF[ni][1] = *(const half8*)(smem + bof1 + ni * 2048);
        }
#pragma unroll
        for (int mi = 0; mi < 4; ++mi) {
            aF[mi][0] = *(const half8*)(smem + aof0 + mi * 2048);
            aF[mi][1] = *(const half8*)(smem + aof1 + mi * 2048);
        }

        // (2b) RSA: convert + swizzled LDS writes for tile t+1 (after reads,
        // so MFMA's lgkm wait only counts the 4 outstanding writes)
        if (RSA && t + 1 < NT16) rsaWrite(fv, nxt);

        // (3) MFMA of tile t (two 32-MFMA halves)
#pragma unroll
        for (int mi = 0; mi < 4; ++mi)
#pragma unroll
            for (int ni = 0; ni < 4; ++ni)
#pragma unroll
                for (int ks = 0; ks < 2; ++ks)
                    acc[mi][ni] = __builtin_amdgcn_mfma_f32_16x16x32_f16(
                        aF[mi][ks], bF[ni][ks], acc[mi][ni], 0, 0, 0);
#pragma unroll
        for (int mi = 0; mi < 4; ++mi) {
            aF[mi][0] = *(const half8*)(smem + aof0 + (4 + mi) * 2048);
            aF[mi][1] = *(const half8*)(smem + aof1 + (4 + mi) * 2048);
        }
#pragma unroll
        for (int mi = 0; mi < 4; ++mi)
#pragma unroll
            for (int ni = 0; ni < 4; ++ni)
#pragma unroll
                for (int ks = 0; ks < 2; ++ks)
                    acc[4 + mi][ni] = __builtin_amdgcn_mfma_f32_16x16x32_f16(
                        aF[mi][ks], bF[ni][ks], acc[4 + mi][ni], 0, 0, 0);

        // (4) one barrier per K-step
        __syncthreads();
        aof0 ^= 65536; aof1 ^= 65536; bof0 ^= 65536; bof1 ^= 65536;
    }

    // ---- epilogue: transpose acc through LDS for coalesced 16B stores.
    {
        float* wlds = (float*)(smem + wave * 2304);   // per-wave 16x36 f32
        float bv[4];
#pragma unroll
        for (int n = 0; n < 4; ++n)
            bv[n] = bias ? bias[col0 + wc * 64 + n * 16 + lr] : 0.f;
        const int er = lane >> 2, ec = lane & 3;
        const int oc = lane >> 1, tc = lane & 1;
#pragma unroll
        for (int m = 0; m < 8; ++m) {
#pragma unroll
            for (int np = 0; np < 2; ++np) {
#pragma unroll
                for (int n2 = 0; n2 < 2; ++n2)
#pragma unroll
                    for (int j = 0; j < 4; ++j)
                        wlds[(lg * 4 + j) * 36 + n2 * 16 + lr] =
                            acc[m][np * 2 + n2][j] + bv[np * 2 + n2];
                const int grow = row0 + wr * 128 + m * 16;
                const int gcol = col0 + wc * 64 + np * 32;
                float4 q0 = *(float4*)&wlds[er * 36 + ec * 8];
                float4 q1 = *(float4*)&wlds[er * 36 + ec * 8 + 4];
                if (WF32) {
                    float* p = Cf + batch * cfBatch + (long)(grow + er) * ldcf + gcol + ec * 8;
                    *(float4*)p = q0;
                    *(float4*)(p + 4) = q1;
                }
                if (WH16) {
                    half8 o = { (half_t)q0.x, (half_t)q0.y, (half_t)q0.z, (half_t)q0.w,
                                (half_t)q1.x, (half_t)q1.y, (half_t)q1.z, (half_t)q1.w };
                    *(half8*)&Ch[(long)(grow + er) * N + gcol + ec * 8] = o;
                }
                if (WH16T) {
                    float tv[8];
#pragma unroll
                    for (int k = 0; k < 8; ++k)
                        tv[k] = wlds[(tc * 8 + k) * 36 + oc];
                    half8 o = { (half_t)tv[0], (half_t)tv[1], (half_t)tv[2], (half_t)tv[3],
                                (half_t)tv[4], (half_t)tv[5], (half_t)tv[6], (half_t)tv[7] };
                    const int gt = grow + tc * 8;
                    *(half8*)&ChT[(long)(gt >> 10) * 1048576
                                  + (long)(gcol + oc) * 1024 + (gt & 1023)] = o;
                }
                __builtin_amdgcn_s_waitcnt(0);   // drain before next overwrite of wlds
            }
        }
    }
}

// In-place: reads f32 row (1024), writes fp16 probabilities over its own first half.
__global__ void softmax_inplace(float* __restrict__ S) {
    const long r = blockIdx.x;
    float* row = S + r * 1024;
    const int tid = threadIdx.x;
    const int wave = tid >> 6, lane = tid & 63;

    float4 v = ((const float4*)row)[tid];
    float mx = fmaxf(fmaxf(v.x, v.y), fmaxf(v.z, v.w));
#pragma unroll
    for (int off = 32; off > 0; off >>= 1)
        mx = fmaxf(mx, __shfl_xor(mx, off));
    __shared__ float rmx[4], rsm[4];
    if (lane == 0) rmx[wave] = mx;
    __syncthreads();
    mx = fmaxf(fmaxf(rmx[0], rmx[1]), fmaxf(rmx[2], rmx[3]));

    float e0 = __expf(v.x - mx), e1 = __expf(v.y - mx);
    float e2 = __expf(v.z - mx), e3 = __expf(v.w - mx);
    float s = e0 + e1 + e2 + e3;
#pragma unroll
    for (int off = 32; off > 0; off >>= 1)
        s += __shfl_xor(s, off);
    if (lane == 0) rsm[wave] = s;
    __syncthreads();
    s = rsm[0] + rsm[1] + rsm[2] + rsm[3];

    const float inv = 1.0f / s;
    half4 o = { (half_t)(e0 * inv), (half_t)(e1 * inv), (half_t)(e2 * inv), (half_t)(e3 * inv) };
    ((half4*)((half_t*)S + r * 2048))[tid] = o;
}

__global__ void cvt_f16(const float4* __restrict__ src, half4* __restrict__ dst, int n4) {
    const int stride = gridDim.x * blockDim.x;
    for (int i = blockIdx.x * blockDim.x + threadIdx.x; i < n4; i += stride) {
        float4 v = src[i];
        half4 o = { (half_t)v.x, (half_t)v.y, (half_t)v.z, (half_t)v.w };
        dst[i] = o;
    }
}

extern "C" void kernel_launch(void* const* d_in, const int* in_sizes, int n_in,
                              void* d_out, int out_size, void* d_ws, size_t ws_size,
                              hipStream_t stream) {
    const float* h  = (const float*)d_in[0];
    const float* s  = (const float*)d_in[1];
    const float* Wh = (const float*)d_in[2];
    const float* bh = (const float*)d_in[3];
    const float* Ws = (const float*)d_in[4];
    const float* bs = (const float*)d_in[5];

    const long MB = 16384;   // B*TH
    const long D  = 1024;

    // workspace carve (~164 MB)
    char* w = (char*)d_ws;
    float*  sc   = (float*)w;   w += MB * D * 4;   // 64MB scores (fp16 probs in place)
    half_t* Wh16 = (half_t*)w;  w += D * D * 2;
    half_t* Ws16 = (half_t*)w;  w += D * D * 2;
    half_t* hp16 = (half_t*)w;  w += MB * D * 2;   // [16384][1024]
    half_t* sp16 = (half_t*)w;  w += MB * D * 2;
    half_t* hpT  = (half_t*)w;  w += MB * D * 2;   // [16][o][t]

    (void)hipFuncSetAttribute(reinterpret_cast<const void*>(&gemm256<0,1,1,1,0>),
                        hipFuncAttributeMaxDynamicSharedMemorySize, 131072);
    (void)hipFuncSetAttribute(reinterpret_cast<const void*>(&gemm256<0,1,0,1,0>),
                        hipFuncAttributeMaxDynamicSharedMemorySize, 131072);
    (void)hipFuncSetAttribute(reinterpret_cast<const void*>(&gemm256<1,0,0,0,1>),
                        hipFuncAttributeMaxDynamicSharedMemorySize, 131072);

    cvt_f16<<<512, 256, 0, stream>>>((const float4*)Wh, (half4*)Wh16, (int)(D * D / 4));
    cvt_f16<<<512, 256, 0, stream>>>((const float4*)Ws, (half4*)Ws16, (int)(D * D / 4));

    // GEMM1: hp = h*Wh^T + bh (A from f32, fused cvt; fp16 out + transposed copy)
    gemm256<0,1,1,1,0><<<dim3(64, 4, 1), 512, 131072, stream>>>(
        nullptr, h, Wh16, bh, nullptr, hp16, hpT, 1024, 1024, 1024, 0, 0, 0, 0);
    // GEMM2: sp = s*Ws^T + bs
    gemm256<0,1,0,1,0><<<dim3(64, 4, 1), 512, 131072, stream>>>(
        nullptr, s, Ws16, bs, nullptr, sp16, nullptr, 1024, 1024, 1024, 0, 0, 0, 0);
    // GEMM3: scores[b] = hp_b * sp_b^T (f32), XCD-batch swizzle
    gemm256<1,0,0,0,1><<<dim3(4, 4, 16), 512, 131072, stream>>>(
        hp16, nullptr, sp16, nullptr, sc, nullptr, nullptr, 1024, 1024, 1024,
        1048576L, 1048576L, 1048576L, 1024);
    // softmax over j, fp16 probs in place (row stride 2048 halves)
    softmax_inplace<<<16384, 256, 0, stream>>>(sc);
    // GEMM4: out[b] = probs_b * hpT_b^T (f32 -> d_out), XCD-batch swizzle
    gemm256<1,0,0,0,1><<<dim3(4, 4, 16), 512, 131072, stream>>>(
        (const half_t*)sc, nullptr, hpT, nullptr, (float*)d_out, nullptr, nullptr,
        2048, 1024, 1024, 2097152L, 1048576L, 1048576L, 1024);
}